// Round 8
// baseline (125.321 us; speedup 1.0000x reference)
//
#include <hip/hip_runtime.h>
#include <hip/hip_fp16.h>
#include <math.h>

#define PATCH 41
#define PP 1681          // 41*41
#define NB 8
#define STRIDE 10
#define PAD 4
#define NTH 192          // 3 waves
#define XROW 52          // padded x row stride in halfs: cols -6..45, index = col+6
#define XSZ (PATCH * XROW)

__device__ __forceinline__ constexpr float tri16(int k) {
    float d = (float)k + 0.5f - 8.0f;
    float a = d < 0.0f ? -d : d;
    return (8.0f - a) * 0.125f;   // u[i]*u[j] == pk[i][j] bit-exactly
}

// per-pixel core: grad + gauss*tri weight -> packed 8-bin f16 contrib (16B)
// (octant-direct binning + 64-bit-shift pack: validated R5-R7)
__device__ __forceinline__ uint4 pixel_contrib(float gx, float gy, float gauss) {
    float X = gx + 1e-10f;
    float mag = __builtin_amdgcn_sqrtf(fmaf(gx, gx, fmaf(gy, gy, 1e-10f))) * gauss;

    float ax = fabsf(X), ay = fabsf(gy);
    float mx = fmaxf(ax, ay), mn = fminf(ax, ay);
    float r = mn * __builtin_amdgcn_rcpf(fmaxf(mx, 1e-30f));
    float r2 = r * r;
    float a4 = fmaf(r2, -0.0149238f, 0.0670406f);
    a4 = fmaf(r2, a4, -0.1482457f);
    a4 = fmaf(r2, a4, 0.2464287f);
    a4 = fmaf(r2, a4, -0.4235106f);
    a4 = fmaf(r2, a4, 1.2732106f);
    a4 *= r;

    bool sw = ay > ax;
    bool xn = X < 0.0f;
    bool yn = gy < 0.0f;
    int q = (xn ? 2 : 0) + ((sw != xn) ? 1 : 0);
    int b0 = yn ? 7 - q : q;              // bin for (1-w1) mass
    bool f = (sw != xn) != yn;
    float ma = a4 * mag;
    float mb = mag - ma;
    float v0 = f ? ma : mb;               // mass for bin b0
    float v1 = f ? mb : ma;               // mass for bin (b0+1)&7

    unsigned combo = __builtin_bit_cast(unsigned, __builtin_amdgcn_cvt_pkrtz(v0, v1));
    int sh = (b0 & 3) << 4;
    unsigned long long A = (unsigned long long)combo << sh;
    unsigned long long B = ((b0 & 3) == 3) ? (unsigned long long)(combo >> 16) : 0ull;
    bool lohalf = b0 < 4;
    unsigned long long lo = lohalf ? A : B;
    unsigned long long hi = lohalf ? B : A;
    uint4 cw;
    cw.x = (unsigned)lo; cw.y = (unsigned)(lo >> 32);
    cw.z = (unsigned)hi; cw.w = (unsigned)(hi >> 32);
    return cw;
}

__global__ __launch_bounds__(NTH, 6) void sift_desc_kernel(
        const float* __restrict__ x,   // [N,1,41,41]
        const float* __restrict__ gk,  // unused: recomputed via exp2
        const float* __restrict__ pk,  // unused: recomputed exactly
        float* __restrict__ out)       // [N,128]
{
    const int patch = blockIdx.x;
    const int t = threadIdx.x;

    __shared__ __align__(16) __half s_xp[XSZ];           // 4.3 KB padded f16 patch
    __shared__ __align__(16) __half s_cw[XROW];          // col gauss, f16, idx=col+6
    __shared__ __align__(16) __half s_H[PATCH * 4 * NB]; // 2.6 KB H[row][ox][bin]
    __shared__ float s_desc[128];

    // ---- P0: padded f16 patch (edge-replicated cols) + col-gauss table ----
    const float* xp = x + (size_t)patch * PP;
    for (int idx = t; idx < XSZ; idx += NTH) {
        int i = idx / XROW;
        int c = idx - i * XROW - 6;                // col in [-6, 45]
        int jc = min(max(c, 0), PATCH - 1);
        s_xp[idx] = __float2half(xp[i * PATCH + jc]);
    }
    if (t < XROW) {
        float dj = (float)(t - 26);                // col = t-6, dj = col-20
        s_cw[t] = __float2half(__builtin_amdgcn_exp2f(dj * dj * -8.582362e-4f));
    }
    __syncthreads();

    // ---- P1+P2 fused: thread = (row, ox). Slide a 3-row register window
    //      over the 16-col span; fold tri*gauss weight into mag; accumulate
    //      all 8 bins in 4 packed f16 regs. No contrib array, no atomics. ----
    if (t < PATCH * 4) {
        const int row = t >> 2;
        const int ox = t & 3;
        const int jw0 = ox * STRIDE - PAD;         // even; window cols jw0..jw0+15
        const int base = jw0 + 6;                  // even half-index of col jw0
        const int rowM = row * XROW;
        const int rowU = (row > 0 ? row - 1 : 0) * XROW;
        const int rowD = (row < PATCH - 1 ? row + 1 : PATCH - 1) * XROW;
        const bool zlo = (ox == 0);
        const bool zhi = (ox == 3);

        float drow = (float)(row - 20);
        const float rf = __builtin_amdgcn_exp2f(drow * drow * -8.582362e-4f);

        // init sliding window: pm = cols (jw0-2, jw0-1), cm = (jw0, jw0+1)
        __half2 pmh = *(const __half2*)&s_xp[rowM + base - 2];
        __half2 cmh = *(const __half2*)&s_xp[rowM + base];
        float pm0 = __low2float(pmh), pm1 = __high2float(pmh);
        float cm0 = __low2float(cmh), cm1 = __high2float(cmh);

        const __half2 z2 = __float2half2_rn(0.0f);
        __half2 a0 = z2, a1 = z2, a2 = z2, a3 = z2;

        #pragma unroll
        for (int it = 0; it < 8; ++it) {
            const int kx0 = 2 * it;
            __half2 nmh = *(const __half2*)&s_xp[rowM + base + kx0 + 2];
            __half2 uh  = *(const __half2*)&s_xp[rowU + base + kx0];
            __half2 dh  = *(const __half2*)&s_xp[rowD + base + kx0];
            __half2 cwh = *(const __half2*)&s_cw[base + kx0];

            __half2 gyh = __hsub2(dh, uh);
            float gy0 = __low2float(gyh), gy1 = __high2float(gyh);
            float nm0 = __low2float(nmh), nm1 = __high2float(nmh);
            float cf0 = __low2float(cwh), cf1 = __high2float(cwh);

            float w0 = tri16(kx0);
            float w1 = tri16(kx0 + 1);
            if (kx0 < 4)      { w0 = zlo ? 0.0f : w0; w1 = zlo ? 0.0f : w1; }
            if (kx0 + 1 == 15){ w1 = zhi ? 0.0f : w1; }

            uint4 c0 = pixel_contrib(cm1 - pm1, gy0, rf * (w0 * cf0));
            uint4 c1 = pixel_contrib(nm0 - cm0, gy1, rf * (w1 * cf1));

            a0 = __hadd2(a0, __hadd2(*(__half2*)&c0.x, *(__half2*)&c1.x));
            a1 = __hadd2(a1, __hadd2(*(__half2*)&c0.y, *(__half2*)&c1.y));
            a2 = __hadd2(a2, __hadd2(*(__half2*)&c0.z, *(__half2*)&c1.z));
            a3 = __hadd2(a3, __hadd2(*(__half2*)&c0.w, *(__half2*)&c1.w));

            pm0 = cm0; pm1 = cm1;
            cm0 = nm0; cm1 = nm1;
        }

        uint4 hv;
        hv.x = *(unsigned*)&a0;
        hv.y = *(unsigned*)&a1;
        hv.z = *(unsigned*)&a2;
        hv.w = *(unsigned*)&a3;
        *(uint4*)&s_H[(row * 4 + ox) * NB] = hv;   // H[row][ox][8 bins f16]
    }
    __syncthreads();

    // ---- P3: vertical triangular pool, f32 accumulate (128 active) ----
    if (t < 128) {
        int b = t >> 4;
        int oy = (t >> 2) & 3;
        int ox = t & 3;
        float v = 0.0f;
        #pragma unroll
        for (int ky = 0; ky < 16; ++ky) {
            const float w = tri16(ky);
            int iy = oy * STRIDE - PAD + ky;
            int iyc = min(max(iy, 0), PATCH - 1);
            float hv = __half2float(s_H[(iyc * 4 + ox) * NB + b]);
            v = fmaf((iy == iyc) ? w : 0.0f, hv, v);
        }
        s_desc[t] = v;
    }
    __syncthreads();

    // ---- P4: single-wave normalization chain + store ----
    if (t < 64) {
        float a = s_desc[t];
        float b = s_desc[t + 64];

        float ss = fmaf(a, a, b * b);
        #pragma unroll
        for (int o = 32; o > 0; o >>= 1) ss += __shfl_xor(ss, o);
        float inv = 1.0f / fmaxf(__builtin_amdgcn_sqrtf(ss), 1e-12f);
        a = fminf(fmaxf(a * inv, 0.0f), 0.2f);
        b = fminf(fmaxf(b * inv, 0.0f), 0.2f);

        float ss2 = fmaf(a, a, b * b);
        #pragma unroll
        for (int o = 32; o > 0; o >>= 1) ss2 += __shfl_xor(ss2, o);
        float inv2 = 1.0f / fmaxf(__builtin_amdgcn_sqrtf(ss2), 1e-12f);
        a *= inv2; b *= inv2;

        float l1 = a + b;                      // a,b >= 0 after clip
        #pragma unroll
        for (int o = 32; o > 0; o >>= 1) l1 += __shfl_xor(l1, o);
        float invl = 1.0f / fmaxf(l1, 1e-12f);

        float* op = out + (size_t)patch * 128;
        op[t]      = __builtin_amdgcn_sqrtf(fmaf(a, invl, 1e-10f));
        op[t + 64] = __builtin_amdgcn_sqrtf(fmaf(b, invl, 1e-10f));
    }
}

extern "C" void kernel_launch(void* const* d_in, const int* in_sizes, int n_in,
                              void* d_out, int out_size, void* d_ws, size_t ws_size,
                              hipStream_t stream) {
    const float* x  = (const float*)d_in[0];
    const float* gk = (const float*)d_in[1];
    const float* pk = (const float*)d_in[2];
    float* out = (float*)d_out;
    const int n = in_sizes[0] / PP;   // 8192 patches
    sift_desc_kernel<<<n, NTH, 0, stream>>>(x, gk, pk, out);
}

// Round 9
// 120.248 us; speedup vs baseline: 1.0422x; 1.0422x over previous
//
#include <hip/hip_runtime.h>
#include <hip/hip_fp16.h>
#include <math.h>

#define PATCH 41
#define PP 1681          // 41*41
#define NB 8
#define STRIDE 10
#define PAD 4
#define NTH 192          // 3 waves
#define XR 50            // f32 row stride; phys col = j+6, j in [-6,43]
#define HR 5             // s_H ox-slot stride (4 used + 1 pad)

__device__ __forceinline__ constexpr float tri16(int k) {
    float d = (float)k + 0.5f - 8.0f;
    float a = d < 0.0f ? -d : d;
    return (8.0f - a) * 0.125f;   // u[i]*u[j] == pk[i][j] bit-exactly
}

// per-pixel core: grad + folded weight -> packed 8-bin f16 contrib (16B)
// (octant-direct binning + 64-bit-shift pack: validated R5-R8)
__device__ __forceinline__ uint4 pixel_contrib(float gx, float gy, float w) {
    float X = gx + 1e-10f;
    float mag = __builtin_amdgcn_sqrtf(fmaf(gx, gx, fmaf(gy, gy, 1e-10f))) * w;

    float ax = fabsf(X), ay = fabsf(gy);
    float mx = fmaxf(ax, ay), mn = fminf(ax, ay);
    float r = mn * __builtin_amdgcn_rcpf(fmaxf(mx, 1e-30f));
    float r2 = r * r;
    float a4 = fmaf(r2, -0.0149238f, 0.0670406f);
    a4 = fmaf(r2, a4, -0.1482457f);
    a4 = fmaf(r2, a4, 0.2464287f);
    a4 = fmaf(r2, a4, -0.4235106f);
    a4 = fmaf(r2, a4, 1.2732106f);
    a4 *= r;

    bool sw = ay > ax;
    bool xn = X < 0.0f;
    bool yn = gy < 0.0f;
    int q = (xn ? 2 : 0) + ((sw != xn) ? 1 : 0);
    int b0 = yn ? 7 - q : q;              // bin for (1-w1) mass
    bool f = (sw != xn) != yn;
    float ma = a4 * mag;
    float mb = mag - ma;
    float v0 = f ? ma : mb;               // mass for bin b0
    float v1 = f ? mb : ma;               // mass for bin (b0+1)&7

    unsigned combo = __builtin_bit_cast(unsigned, __builtin_amdgcn_cvt_pkrtz(v0, v1));
    int sh = (b0 & 3) << 4;
    unsigned long long A = (unsigned long long)combo << sh;
    unsigned long long B = ((b0 & 3) == 3) ? (unsigned long long)(combo >> 16) : 0ull;
    bool lohalf = b0 < 4;
    unsigned long long lo = lohalf ? A : B;
    unsigned long long hi = lohalf ? B : A;
    uint4 cw;
    cw.x = (unsigned)lo; cw.y = (unsigned)(lo >> 32);
    cw.z = (unsigned)hi; cw.w = (unsigned)(hi >> 32);
    return cw;
}

__global__ __launch_bounds__(NTH, 6) void sift_desc_kernel(
        const float* __restrict__ x,   // [N,1,41,41]
        const float* __restrict__ gk,  // unused: recomputed via exp2
        const float* __restrict__ pk,  // unused: recomputed exactly
        float* __restrict__ out)       // [N,128]
{
    const int patch = blockIdx.x;
    const int t = threadIdx.x;

    __shared__ __align__(16) float s_xp[PATCH * XR];     // 8.2 KB f32 padded patch
    __shared__ __align__(16) float s_wl[64];             // wl[ox][kx]: tri*gauss*mask
    __shared__ __align__(16) __half s_H[49 * HR * NB];   // 3.9 KB, rows 0-3,45+ zero
    __shared__ float s_desc[128];

    // ---- P0: stage patch (coalesced bulk + small pad pass), LUT, H-pad ----
    const float* xp = x + (size_t)patch * PP;
    for (int p = t; p < PP; p += NTH) {
        int i = p / PATCH;
        int j = p - i * PATCH;
        s_xp[i * XR + j + 6] = xp[p];
    }
    for (int q = t; q < 41 * 9; q += NTH) {        // pad cols j=-6..-1,41..43
        int i = q / 9;
        int c = q - i * 9;
        int j = (c < 6) ? (c - 6) : (c + 35);
        int jc = min(max(j, 0), PATCH - 1);
        s_xp[i * XR + j + 6] = xp[i * PATCH + jc];
    }
    if (t < 64) {                                   // weight LUT
        int ox = t >> 4, kx = t & 15;
        int col = ox * STRIDE - PAD + kx;
        float d = (float)(col - 20);
        float g = __builtin_amdgcn_exp2f(d * d * -8.582362e-4f);
        bool oob = (col < 0) | (col > PATCH - 1);
        s_wl[t] = oob ? 0.0f : tri16(kx) * g;
    }
    if (t < 160) {                                  // zero H pad rows 0-3,45-48
        int dw = (t < 80) ? t : (820 + t);
        ((unsigned*)s_H)[dw] = 0u;
    }
    __syncthreads();

    // ---- P1+P2 fused: thread=(row,ox), f32 sliding window, LUT weights ----
    if (t < PATCH * 4) {
        const int row = t >> 2;
        const int ox = t & 3;
        const int rowM = row * XR + ox * STRIDE + 2;           // phys idx of col jw0
        const int rowU = (row > 0 ? row - 1 : 0) * XR + ox * STRIDE + 2;
        const int rowD = (row < PATCH - 1 ? row + 1 : PATCH - 1) * XR + ox * STRIDE + 2;

        float drow = (float)(row - 20);
        const float rf = __builtin_amdgcn_exp2f(drow * drow * -8.582362e-4f);

        float wf[16];
        {
            const float4* wl4 = (const float4*)&s_wl[ox << 4];
            float4 w0 = wl4[0], w1 = wl4[1], w2 = wl4[2], w3 = wl4[3];
            wf[0] = w0.x * rf;  wf[1] = w0.y * rf;  wf[2] = w0.z * rf;  wf[3] = w0.w * rf;
            wf[4] = w1.x * rf;  wf[5] = w1.y * rf;  wf[6] = w1.z * rf;  wf[7] = w1.w * rf;
            wf[8] = w2.x * rf;  wf[9] = w2.y * rf;  wf[10] = w2.z * rf; wf[11] = w2.w * rf;
            wf[12] = w3.x * rf; wf[13] = w3.y * rf; wf[14] = w3.z * rf; wf[15] = w3.w * rf;
        }

        float2 pm = *(const float2*)&s_xp[rowM - 2];
        float2 cm = *(const float2*)&s_xp[rowM];

        const __half2 z2 = __float2half2_rn(0.0f);
        __half2 a0 = z2, a1 = z2, a2 = z2, a3 = z2;

        #pragma unroll
        for (int it = 0; it < 8; ++it) {
            const int kx0 = 2 * it;
            float2 nm = *(const float2*)&s_xp[rowM + kx0 + 2];
            float2 uu = *(const float2*)&s_xp[rowU + kx0];
            float2 dd = *(const float2*)&s_xp[rowD + kx0];

            uint4 c0 = pixel_contrib(cm.y - pm.y, dd.x - uu.x, wf[kx0]);
            uint4 c1 = pixel_contrib(nm.x - cm.x, dd.y - uu.y, wf[kx0 + 1]);

            a0 = __hadd2(a0, __hadd2(*(__half2*)&c0.x, *(__half2*)&c1.x));
            a1 = __hadd2(a1, __hadd2(*(__half2*)&c0.y, *(__half2*)&c1.y));
            a2 = __hadd2(a2, __hadd2(*(__half2*)&c0.z, *(__half2*)&c1.z));
            a3 = __hadd2(a3, __hadd2(*(__half2*)&c0.w, *(__half2*)&c1.w));

            pm = cm;
            cm = nm;
        }

        uint4 hv;
        hv.x = *(unsigned*)&a0;
        hv.y = *(unsigned*)&a1;
        hv.z = *(unsigned*)&a2;
        hv.w = *(unsigned*)&a3;
        *(uint4*)&s_H[((row + 4) * HR + ox) * NB] = hv;   // phys row = row+4
    }
    __syncthreads();

    // ---- P3: vertical pool over zero-padded H: no clamps, pure fma ----
    if (t < 128) {
        int b = t >> 4;
        int oy = (t >> 2) & 3;
        int ox = t & 3;
        const __half* hp = &s_H[(oy * STRIDE * HR + ox) * NB + b]; // phys row oy*10
        float v = 0.0f;
        #pragma unroll
        for (int ky = 0; ky < 16; ++ky) {
            v = fmaf(tri16(ky), __half2float(hp[ky * HR * NB]), v);
        }
        s_desc[t] = v;
    }
    __syncthreads();

    // ---- P4: single-wave normalization chain + store ----
    if (t < 64) {
        float a = s_desc[t];
        float b = s_desc[t + 64];

        float ss = fmaf(a, a, b * b);
        #pragma unroll
        for (int o = 32; o > 0; o >>= 1) ss += __shfl_xor(ss, o);
        float inv = 1.0f / fmaxf(__builtin_amdgcn_sqrtf(ss), 1e-12f);
        a = fminf(fmaxf(a * inv, 0.0f), 0.2f);
        b = fminf(fmaxf(b * inv, 0.0f), 0.2f);

        float ss2 = fmaf(a, a, b * b);
        #pragma unroll
        for (int o = 32; o > 0; o >>= 1) ss2 += __shfl_xor(ss2, o);
        float inv2 = 1.0f / fmaxf(__builtin_amdgcn_sqrtf(ss2), 1e-12f);
        a *= inv2; b *= inv2;

        float l1 = a + b;                      // a,b >= 0 after clip
        #pragma unroll
        for (int o = 32; o > 0; o >>= 1) l1 += __shfl_xor(l1, o);
        float invl = 1.0f / fmaxf(l1, 1e-12f);

        float* op = out + (size_t)patch * 128;
        op[t]      = __builtin_amdgcn_sqrtf(fmaf(a, invl, 1e-10f));
        op[t + 64] = __builtin_amdgcn_sqrtf(fmaf(b, invl, 1e-10f));
    }
}

extern "C" void kernel_launch(void* const* d_in, const int* in_sizes, int n_in,
                              void* d_out, int out_size, void* d_ws, size_t ws_size,
                              hipStream_t stream) {
    const float* x  = (const float*)d_in[0];
    const float* gk = (const float*)d_in[1];
    const float* pk = (const float*)d_in[2];
    float* out = (float*)d_out;
    const int n = in_sizes[0] / PP;   // 8192 patches
    sift_desc_kernel<<<n, NTH, 0, stream>>>(x, gk, pk, out);
}

// Round 10
// 117.604 us; speedup vs baseline: 1.0656x; 1.0225x over previous
//
#include <hip/hip_runtime.h>
#include <hip/hip_fp16.h>
#include <math.h>

#define PATCH 41
#define PP 1681          // 41*41
#define NB 8
#define STRIDE 10
#define PAD 4
#define NTH 192          // 3 waves
#define XR 51            // f32 row stride (ODD: mixed-parity banks); phys col = j+6
#define HR 5             // s_H ox-slot stride (4 used + 1 pad)

__device__ __forceinline__ constexpr float tri16(int k) {
    float d = (float)k + 0.5f - 8.0f;
    float a = d < 0.0f ? -d : d;
    return (8.0f - a) * 0.125f;   // u[i]*u[j] == pk[i][j] bit-exactly
}

// per-pixel core: grad + folded weight -> packed 8-bin f16 contrib (16B)
// (octant-direct binning + 64-bit-shift pack: validated R5-R9)
__device__ __forceinline__ uint4 pixel_contrib(float gx, float gy, float w) {
    float X = gx + 1e-10f;
    float mag = __builtin_amdgcn_sqrtf(fmaf(gx, gx, fmaf(gy, gy, 1e-10f))) * w;

    float ax = fabsf(X), ay = fabsf(gy);
    float mx = fmaxf(ax, ay), mn = fminf(ax, ay);
    float r = mn * __builtin_amdgcn_rcpf(fmaxf(mx, 1e-30f));
    float r2 = r * r;
    float a4 = fmaf(r2, -0.0149238f, 0.0670406f);
    a4 = fmaf(r2, a4, -0.1482457f);
    a4 = fmaf(r2, a4, 0.2464287f);
    a4 = fmaf(r2, a4, -0.4235106f);
    a4 = fmaf(r2, a4, 1.2732106f);
    a4 *= r;

    bool sw = ay > ax;
    bool xn = X < 0.0f;
    bool yn = gy < 0.0f;
    int q = (xn ? 2 : 0) + ((sw != xn) ? 1 : 0);
    int b0 = yn ? 7 - q : q;              // bin for (1-w1) mass
    bool f = (sw != xn) != yn;
    float ma = a4 * mag;
    float mb = mag - ma;
    float v0 = f ? ma : mb;               // mass for bin b0
    float v1 = f ? mb : ma;               // mass for bin (b0+1)&7

    unsigned combo = __builtin_bit_cast(unsigned, __builtin_amdgcn_cvt_pkrtz(v0, v1));
    int sh = (b0 & 3) << 4;
    unsigned long long A = (unsigned long long)combo << sh;
    unsigned long long B = ((b0 & 3) == 3) ? (unsigned long long)(combo >> 16) : 0ull;
    bool lohalf = b0 < 4;
    unsigned long long lo = lohalf ? A : B;
    unsigned long long hi = lohalf ? B : A;
    uint4 cw;
    cw.x = (unsigned)lo; cw.y = (unsigned)(lo >> 32);
    cw.z = (unsigned)hi; cw.w = (unsigned)(hi >> 32);
    return cw;
}

__global__ __launch_bounds__(NTH, 8) void sift_desc_kernel(
        const float* __restrict__ x,   // [N,1,41,41]
        const float* __restrict__ gk,  // unused: recomputed via exp2
        const float* __restrict__ pk,  // unused: recomputed exactly
        float* __restrict__ out)       // [N,128]
{
    const int patch = blockIdx.x;
    const int t = threadIdx.x;

    __shared__ __align__(16) float s_xp[PATCH * XR];     // 8.4 KB f32 padded patch
    __shared__ __align__(16) float s_wl[64];             // wl[ox][kx]: tri*gauss*mask
    __shared__ __align__(16) __half s_H[49 * HR * NB];   // 3.9 KB, rows 0-3,45+ zero
    __shared__ float s_desc[128];

    // ---- P0: stage patch (incremental i,j), LUT, H-pad ----
    const float* xp = x + (size_t)patch * PP;
    {
        int i = t / PATCH;
        int j = t - i * PATCH;
        for (int p = t; p < PP; p += NTH) {
            s_xp[i * XR + j + 6] = xp[p];
            j += 28; i += 4;                       // 192 = 4*41 + 28
            if (j >= PATCH) { j -= PATCH; i += 1; }
        }
    }
    for (int q = t; q < 41 * 9; q += NTH) {        // pad cols j=-6..-1,41..43
        int i = q / 9;
        int c = q - i * 9;
        int j = (c < 6) ? (c - 6) : (c + 35);
        int jc = min(max(j, 0), PATCH - 1);
        s_xp[i * XR + j + 6] = xp[i * PATCH + jc];
    }
    if (t < 64) {                                   // weight LUT
        int ox = t >> 4, kx = t & 15;
        int col = ox * STRIDE - PAD + kx;
        float d = (float)(col - 20);
        float g = __builtin_amdgcn_exp2f(d * d * -8.582362e-4f);
        bool oob = (col < 0) | (col > PATCH - 1);
        s_wl[t] = oob ? 0.0f : tri16(kx) * g;
    }
    if (t < 160) {                                  // zero H pad rows 0-3,45-48
        int dw = (t < 80) ? t : (820 + t);
        ((unsigned*)s_H)[dw] = 0u;
    }
    __syncthreads();

    // ---- P1+P2 fused: thread=(row,ox), scalar-float sliding window ----
    if (t < PATCH * 4) {
        const int row = t >> 2;
        const int ox = t & 3;
        const int rowM = row * XR + ox * STRIDE + 2;           // phys idx of col jw0
        const int rowU = (row > 0 ? row - 1 : 0) * XR + ox * STRIDE + 2;
        const int rowD = (row < PATCH - 1 ? row + 1 : PATCH - 1) * XR + ox * STRIDE + 2;

        float drow = (float)(row - 20);
        const float rf = __builtin_amdgcn_exp2f(drow * drow * -8.582362e-4f);

        float wf[16];
        {
            const float4* wl4 = (const float4*)&s_wl[ox << 4];
            float4 w0 = wl4[0], w1 = wl4[1], w2 = wl4[2], w3 = wl4[3];
            wf[0] = w0.x * rf;  wf[1] = w0.y * rf;  wf[2] = w0.z * rf;  wf[3] = w0.w * rf;
            wf[4] = w1.x * rf;  wf[5] = w1.y * rf;  wf[6] = w1.z * rf;  wf[7] = w1.w * rf;
            wf[8] = w2.x * rf;  wf[9] = w2.y * rf;  wf[10] = w2.z * rf; wf[11] = w2.w * rf;
            wf[12] = w3.x * rf; wf[13] = w3.y * rf; wf[14] = w3.z * rf; wf[15] = w3.w * rf;
        }

        // sliding columns: xm1 = col kx0-1, x0 = col kx0, x1 = col kx0+1
        float xm1 = s_xp[rowM - 1];
        float x0  = s_xp[rowM];
        float x1  = s_xp[rowM + 1];

        const __half2 z2 = __float2half2_rn(0.0f);
        __half2 a0 = z2, a1 = z2, a2 = z2, a3 = z2;

        #pragma unroll
        for (int it = 0; it < 8; ++it) {
            const int kx0 = 2 * it;
            float x2 = s_xp[rowM + kx0 + 2];
            float x3 = s_xp[rowM + kx0 + 3];
            float u0 = s_xp[rowU + kx0];
            float u1 = s_xp[rowU + kx0 + 1];
            float d0 = s_xp[rowD + kx0];
            float d1 = s_xp[rowD + kx0 + 1];

            uint4 c0 = pixel_contrib(x1 - xm1, d0 - u0, wf[kx0]);
            uint4 c1 = pixel_contrib(x2 - x0,  d1 - u1, wf[kx0 + 1]);

            a0 = __hadd2(a0, __hadd2(*(__half2*)&c0.x, *(__half2*)&c1.x));
            a1 = __hadd2(a1, __hadd2(*(__half2*)&c0.y, *(__half2*)&c1.y));
            a2 = __hadd2(a2, __hadd2(*(__half2*)&c0.z, *(__half2*)&c1.z));
            a3 = __hadd2(a3, __hadd2(*(__half2*)&c0.w, *(__half2*)&c1.w));

            xm1 = x1; x0 = x2; x1 = x3;
        }

        uint4 hv;
        hv.x = *(unsigned*)&a0;
        hv.y = *(unsigned*)&a1;
        hv.z = *(unsigned*)&a2;
        hv.w = *(unsigned*)&a3;
        *(uint4*)&s_H[((row + 4) * HR + ox) * NB] = hv;   // phys row = row+4
    }
    __syncthreads();

    // ---- P3: vertical pool over zero-padded H: no clamps, pure fma ----
    if (t < 128) {
        int b = t >> 4;
        int oy = (t >> 2) & 3;
        int ox = t & 3;
        const __half* hp = &s_H[(oy * STRIDE * HR + ox) * NB + b]; // phys row oy*10
        float v = 0.0f;
        #pragma unroll
        for (int ky = 0; ky < 16; ++ky) {
            v = fmaf(tri16(ky), __half2float(hp[ky * HR * NB]), v);
        }
        s_desc[t] = v;
    }
    __syncthreads();

    // ---- P4: single-wave normalization chain + store ----
    if (t < 64) {
        float a = s_desc[t];
        float b = s_desc[t + 64];

        float ss = fmaf(a, a, b * b);
        #pragma unroll
        for (int o = 32; o > 0; o >>= 1) ss += __shfl_xor(ss, o);
        float inv = 1.0f / fmaxf(__builtin_amdgcn_sqrtf(ss), 1e-12f);
        a = fminf(fmaxf(a * inv, 0.0f), 0.2f);
        b = fminf(fmaxf(b * inv, 0.0f), 0.2f);

        float ss2 = fmaf(a, a, b * b);
        #pragma unroll
        for (int o = 32; o > 0; o >>= 1) ss2 += __shfl_xor(ss2, o);
        float inv2 = 1.0f / fmaxf(__builtin_amdgcn_sqrtf(ss2), 1e-12f);
        a *= inv2; b *= inv2;

        float l1 = a + b;                      // a,b >= 0 after clip
        #pragma unroll
        for (int o = 32; o > 0; o >>= 1) l1 += __shfl_xor(l1, o);
        float invl = 1.0f / fmaxf(l1, 1e-12f);

        float* op = out + (size_t)patch * 128;
        op[t]      = __builtin_amdgcn_sqrtf(fmaf(a, invl, 1e-10f));
        op[t + 64] = __builtin_amdgcn_sqrtf(fmaf(b, invl, 1e-10f));
    }
}

extern "C" void kernel_launch(void* const* d_in, const int* in_sizes, int n_in,
                              void* d_out, int out_size, void* d_ws, size_t ws_size,
                              hipStream_t stream) {
    const float* x  = (const float*)d_in[0];
    const float* gk = (const float*)d_in[1];
    const float* pk = (const float*)d_in[2];
    float* out = (float*)d_out;
    const int n = in_sizes[0] / PP;   // 8192 patches
    sift_desc_kernel<<<n, NTH, 0, stream>>>(x, gk, pk, out);
}